// Round 12
// baseline (480.530 us; speedup 1.0000x reference)
//
#include <hip/hip_runtime.h>
#include <hip/hip_bf16.h>
#include <cstdint>
#include <cstddef>

typedef __bf16 bf16;
typedef __attribute__((ext_vector_type(8))) __bf16 bf16x8;
typedef __attribute__((ext_vector_type(4))) float f32x4;
typedef __attribute__((ext_vector_type(4))) int i32x4;
typedef __attribute__((address_space(3))) const bf16* lds_cp;

#define B_SZ  8192
#define NAGENT 8
#define NA_N  16
#define OBS_DD 2048
#define ACT_DD 128
#define IN_DD 2176
#define H1_D  1024
#define H2_D  1024

#define BM 256
#define BN 256
#define BK 64
#define GRID_M (B_SZ / BM)   // 32
#define GRID_N (1024 / BN)   // 4

__device__ __forceinline__ void gload16(const void* g, void* l) {
    __builtin_amdgcn_global_load_lds(
        (__attribute__((address_space(1))) void*)(g),
        (__attribute__((address_space(3))) void*)(l), 16, 0, 0);
}

// ---------- preprocessing (verified rounds 1-10) ----------

__global__ void k_convert_x(const float* __restrict__ obs,
                            const float* __restrict__ act,
                            bf16* __restrict__ xb) {
    const int chunks = IN_DD / 8;          // 272
    int idx = blockIdx.x * blockDim.x + threadIdx.x;
    if (idx >= B_SZ * chunks) return;
    int b = idx / chunks;
    int c8 = idx - b * chunks;
    const float* src = (c8 < OBS_DD / 8)
        ? (obs + (size_t)b * OBS_DD + c8 * 8)
        : (act + (size_t)b * ACT_DD + (c8 - OBS_DD / 8) * 8);
    float4 v0 = ((const float4*)src)[0];
    float4 v1 = ((const float4*)src)[1];
    bf16x8 o;
    o[0] = (bf16)v0.x; o[1] = (bf16)v0.y; o[2] = (bf16)v0.z; o[3] = (bf16)v0.w;
    o[4] = (bf16)v1.x; o[5] = (bf16)v1.y; o[6] = (bf16)v1.z; o[7] = (bf16)v1.w;
    ((bf16x8*)(xb + (size_t)b * IN_DD))[c8] = o;
}

__global__ void k_transpose_w(const float* __restrict__ src, bf16* __restrict__ dst,
                              int K, int H, int maskStart) {
    __shared__ float tile[32][33];
    int a = blockIdx.z;
    int k0 = blockIdx.x * 32, h0 = blockIdx.y * 32;
    const float* s = src + (size_t)a * K * H;
    bf16* d = dst + (size_t)a * K * H;
    int tx = threadIdx.x, ty = threadIdx.y;
    #pragma unroll
    for (int i = 0; i < 32; i += 8) {
        int k = k0 + ty + i;
        float v = s[(size_t)k * H + h0 + tx];
        if (k >= maskStart) {
            int g = k - maskStart;
            if ((g >> 4) == a) v = 0.f;
        }
        tile[ty + i][tx] = v;
    }
    __syncthreads();
    #pragma unroll
    for (int i = 0; i < 32; i += 8) {
        d[(size_t)(h0 + ty + i) * K + k0 + tx] = (bf16)tile[tx][ty + i];
    }
}

__global__ void k_transpose_w3(const float* __restrict__ src, bf16* __restrict__ dst) {
    int idx = blockIdx.x * blockDim.x + threadIdx.x;
    if (idx >= NAGENT * NA_N * H2_D) return;
    int a = idx / (NA_N * H2_D);
    int n = (idx / H2_D) % NA_N;
    int k = idx % H2_D;
    dst[idx] = (bf16)src[(size_t)a * H2_D * NA_N + (size_t)k * NA_N + n];
}

// out[b, a*16+n] = b3[a,n]  (bias pre-init; fused L3 atomically accumulates)
__global__ void k_init_out(const float* __restrict__ b3, float* __restrict__ out) {
    int i = blockIdx.x * blockDim.x + threadIdx.x;
    if (i < B_SZ * NAGENT * NA_N) out[i] = b3[i & 127];
}

// ---------- 256x256x64 GEMM, 4 waves x 128x128 wave-tile, 1 wave/SIMD ----------
// Halves LDS read amplification (192->128 KB/tile/CU) so the LDS port drops
// below the MFMA pipe. 1 wave/SIMD => 512-reg budget for acc[8][8] (256 VGPR).
// Slots (elems): A: (t&1)*16384 ; B: 32768 + (t&1)*16384. 128 KiB total.
// Wait ledger (all counted lgkm waits <= 8; DS completes in-order, r3-r10):
//   fa(8), fb(8) issued; STAGE; lgkm(4) -> C1a(32); fe(8); lgkm(8) -> C1b(32);
//   ff(8); lgkm(4) -> C2a(32); lgkm(0) -> C2b(32); vmcnt(0); barrier.
#define DSR4(d0, d1, d2, d3, addr, O0, O1, O2, O3)                      \
    asm volatile("ds_read_b128 %0, %4 offset:" #O0 "\n\t"               \
                 "ds_read_b128 %1, %4 offset:" #O1 "\n\t"               \
                 "ds_read_b128 %2, %4 offset:" #O2 "\n\t"               \
                 "ds_read_b128 %3, %4 offset:" #O3                      \
                 : "=&v"(d0), "=&v"(d1), "=&v"(d2), "=&v"(d3)           \
                 : "v"(addr))

#define BC(x) __builtin_bit_cast(bf16x8, x)

template<int FUSE>
__global__ __launch_bounds__(256, 1)
void k_gemm256(const bf16* __restrict__ Ain, size_t aStride, int lda,
               const bf16* __restrict__ Bw, const float* __restrict__ bias,
               bf16* __restrict__ Cout, size_t cStride, int K,
               int aOff, int gridZ,
               const bf16* __restrict__ W3Tp, float* __restrict__ outp) {
    extern __shared__ bf16 lds[];   // 65536 elems = 128 KiB

    const int tid = threadIdx.x;
    const int w = tid >> 6;          // 0..3
    const int l = tid & 63;

    // XCD-chunked remap (nwg = 128*gridZ, % 8 == 0)
    int flat = blockIdx.x + GRID_M * (blockIdx.y + GRID_N * blockIdx.z);
    int q8 = (GRID_M * GRID_N * gridZ) >> 3;
    int lin2 = (flat & 7) * q8 + (flat >> 3);
    const int mt = lin2 % GRID_M;
    int rest = lin2 / GRID_M;
    const int ntile = rest % GRID_N;
    const int az = rest / GRID_N;
    const int aw = az + aOff;

    const int rowBase = mt * BM;
    const int colBase = ntile * BN;
    const bf16* Aag = Ain + (size_t)az * aStride;
    const bf16* Bag = Bw + (size_t)aw * (size_t)1024 * K;

    const int wrq = (w >> 1) * 128;  // wave quadrant rows
    const int wcq = (w & 1) * 128;   // wave quadrant cols
    const int lr = l & 15;
    const int lq = l >> 4;

    // fragment addressing (r6-verified): chunk swizzle phys = logical ^ (row&7);
    // row&7 == lr&7 for all frags (frag strides are multiples of 16 rows).
    const int rowA = (wrq + lr) * BK;
    const int rowB = (wcq + lr) * BK;
    const int ck0 = ((lq ^ (lr & 7)) * 8);
    const int ck1 = (((4 + lq) ^ (lr & 7)) * 8);

    // staging: wave role w covers {A-lo, A-hi, B-lo, B-hi}[w]: 128 rows x 64.
    // gload j: rows j*8 + (l>>3), dest sBase + j*512 + l*8 (lane-linear);
    // source chunk pre-swizzled: logical = (l&7) ^ (l>>3)  (row&7 = l>>3).
    const int sCol = ((l & 7) ^ (l >> 3)) * 8;
    const size_t ldS = (w & 2) ? (size_t)K : (size_t)lda;
    const bf16* pS = (w & 2)
        ? (Bag + (size_t)(colBase + (w & 1) * 128 + (l >> 3)) * K + sCol)
        : (Aag + (size_t)(rowBase + (w & 1) * 128 + (l >> 3)) * lda + sCol);
    const int sBase = ((w & 2) ? 32768 : 0) + (w & 1) * 8192;

    const int nkt = K / BK;

#define STAGE(t1) do {                                                      \
        const bf16* g_ = pS + (size_t)(t1) * BK;                            \
        bf16* d_ = &lds[(((t1) & 1) * 16384) + sBase];                      \
        _Pragma("unroll")                                                   \
        for (int j_ = 0; j_ < 16; ++j_)                                     \
            gload16(g_ + (size_t)j_ * 8 * ldS, d_ + j_ * 512);              \
    } while (0)

    f32x4 acc[8][8] = {};
    i32x4 fa[8], fb[8];   // ks0 frags (A m0-7, B n0-7)
    i32x4 fe[8], ff[8];   // ks1 frags

#define MFMA_BLK(AF, BF, N0)                                                \
    do {                                                                    \
        _Pragma("unroll")                                                   \
        for (int n_ = 0; n_ < 4; ++n_)                                      \
            _Pragma("unroll")                                               \
            for (int m_ = 0; m_ < 8; ++m_)                                  \
                acc[m_][N0 + n_] = __builtin_amdgcn_mfma_f32_16x16x32_bf16( \
                    BC(AF[m_]), BC(BF[N0 + n_]), acc[m_][N0 + n_], 0, 0, 0);\
    } while (0)

    // prologue: stage tile 0, drain, barrier
    STAGE(0);
    asm volatile("s_waitcnt vmcnt(0)" ::: "memory");
    __builtin_amdgcn_s_barrier();

    for (int t = 0; t < nkt; ++t) {
        const int dbuf = (t & 1) * 16384;
        lds_cp adrA0 = (lds_cp)lds + (dbuf + rowA + ck0);
        lds_cp adrA1 = (lds_cp)lds + (dbuf + rowA + ck1);
        lds_cp adrB0 = (lds_cp)lds + (32768 + dbuf + rowB + ck0);
        lds_cp adrB1 = (lds_cp)lds + (32768 + dbuf + rowB + ck1);

        // fa: A ks0 m0-7 (8 reads, oldest); fb: B ks0 n0-7 (8)   [16 out]
        DSR4(fa[0], fa[1], fa[2], fa[3], adrA0, 0, 2048, 4096, 6144);
        DSR4(fa[4], fa[5], fa[6], fa[7], adrA0, 8192, 10240, 12288, 14336);
        DSR4(fb[0], fb[1], fb[2], fb[3], adrB0, 0, 2048, 4096, 6144);
        DSR4(fb[4], fb[5], fb[6], fb[7], adrB0, 8192, 10240, 12288, 14336);

        // stage next tile (vmcnt-counted only; lands during the MFMA body)
        if (t + 1 < nkt) STAGE(t + 1);

        asm volatile("s_waitcnt lgkmcnt(4)" ::: "memory");   // fa + fb[0..3]
        __builtin_amdgcn_sched_barrier(0);
        __builtin_amdgcn_s_setprio(1);
        MFMA_BLK(fa, fb, 0);                                 // C1a: ks0 n0-3
        __builtin_amdgcn_s_setprio(0);

        // fe: A ks1 m0-7 (8)    [4 + 8 out]
        DSR4(fe[0], fe[1], fe[2], fe[3], adrA1, 0, 2048, 4096, 6144);
        DSR4(fe[4], fe[5], fe[6], fe[7], adrA1, 8192, 10240, 12288, 14336);

        asm volatile("s_waitcnt lgkmcnt(8)" ::: "memory");   // fb[4..7] done
        __builtin_amdgcn_sched_barrier(0);
        __builtin_amdgcn_s_setprio(1);
        MFMA_BLK(fa, fb, 4);                                 // C1b: ks0 n4-7
        __builtin_amdgcn_s_setprio(0);

        // ff: B ks1 n0-7 (8)    [8 + 8 out]
        DSR4(ff[0], ff[1], ff[2], ff[3], adrB1, 0, 2048, 4096, 6144);
        DSR4(ff[4], ff[5], ff[6], ff[7], adrB1, 8192, 10240, 12288, 14336);

        asm volatile("s_waitcnt lgkmcnt(4)" ::: "memory");   // fe + ff[0..3]
        __builtin_amdgcn_sched_barrier(0);
        __builtin_amdgcn_s_setprio(1);
        MFMA_BLK(fe, ff, 0);                                 // C2a: ks1 n0-3
        __builtin_amdgcn_s_setprio(0);

        asm volatile("s_waitcnt lgkmcnt(0)" ::: "memory");   // ff[4..7] done
        __builtin_amdgcn_sched_barrier(0);
        __builtin_amdgcn_s_setprio(1);
        MFMA_BLK(fe, ff, 4);                                 // C2b: ks1 n4-7
        __builtin_amdgcn_s_setprio(0);

        asm volatile("s_waitcnt vmcnt(0)" ::: "memory");
        __builtin_amdgcn_s_barrier();
    }
#undef STAGE
#undef MFMA_BLK

    // ---- epilogue: bias + relu -> swizzled C-LDS tile [256][256] bf16
    __syncthreads();
    const float* bAg = bias + (size_t)aw * 1024;
    float bb8[8];
    #pragma unroll
    for (int n = 0; n < 8; ++n) bb8[n] = bAg[colBase + wcq + n * 16 + lr];
    #pragma unroll
    for (int m = 0; m < 8; ++m)
        #pragma unroll
        for (int n = 0; n < 8; ++n)
            #pragma unroll
            for (int r = 0; r < 4; ++r) {
                float v = acc[m][n][r] + bb8[n];
                v = fmaxf(v, 0.f);
                int row = wrq + m * 16 + lq * 4 + r;
                int col = wcq + n * 16 + lr;
                lds[row * 256 + ((((col >> 3) ^ (row & 7)) << 3) | (col & 7))] = (bf16)v;
            }
    __syncthreads();

    if constexpr (!FUSE) {
        bf16* Cg = Cout + (size_t)az * cStride + (size_t)rowBase * 1024 + colBase;
        const int er = tid >> 5;       // 0..7
        const int ec = tid & 31;       // chunk 0..31
        #pragma unroll
        for (int i = 0; i < 32; ++i) {
            int row = i * 8 + er;
            int phys = ec ^ (row & 7);
            *(bf16x8*)&Cg[(size_t)row * 1024 + ec * 8] =
                *(const bf16x8*)&lds[row * 256 + phys * 8];
        }
    } else {
        // fused L3: h2 tile (256 rows, k-slice [colBase,colBase+256)) x W3T[aw]
        // wave w owns rows w*64 .. w*64+63 (4 mm blocks of 16).
        const bf16* w3a = W3Tp + (size_t)aw * NA_N * H2_D;
        f32x4 oacc[4] = {};
        const int frow0 = w * 64;
        #pragma unroll
        for (int ks = 0; ks < 8; ++ks) {
            bf16x8 bfrag = *(const bf16x8*)&w3a[(size_t)lr * H2_D + colBase + ks * 32 + lq * 8];
            #pragma unroll
            for (int mm = 0; mm < 4; ++mm) {
                int row = frow0 + mm * 16 + lr;
                int lc = (ks * 4 + lq) ^ (row & 7);
                bf16x8 afrag = *(const bf16x8*)&lds[row * 256 + lc * 8];
                oacc[mm] = __builtin_amdgcn_mfma_f32_16x16x32_bf16(afrag, bfrag, oacc[mm], 0, 0, 0);
            }
        }
        #pragma unroll
        for (int mm = 0; mm < 4; ++mm)
            #pragma unroll
            for (int r = 0; r < 4; ++r)
                atomicAdd(&outp[(size_t)(rowBase + frow0 + mm * 16 + lq * 4 + r) * 128
                                + aw * NA_N + lr], oacc[mm][r]);
    }
}

// ---------- launcher ----------
extern "C" void kernel_launch(void* const* d_in, const int* in_sizes, int n_in,
                              void* d_out, int out_size, void* d_ws, size_t ws_size,
                              hipStream_t stream) {
    const float* obs = (const float*)d_in[0];
    const float* act = (const float*)d_in[1];
    const float* W1 = (const float*)d_in[2];
    const float* b1 = (const float*)d_in[3];
    const float* W2 = (const float*)d_in[4];
    const float* b2 = (const float*)d_in[5];
    const float* W3 = (const float*)d_in[6];
    const float* b3 = (const float*)d_in[7];
    float* out = (float*)d_out;

    const size_t SZ_XB  = (size_t)B_SZ * IN_DD * 2;
    const size_t SZ_W1T = (size_t)NAGENT * H1_D * IN_DD * 2;
    const size_t SZ_W2T = (size_t)NAGENT * H1_D * H2_D * 2;
    const size_t SZ_W3T = (size_t)NAGENT * NA_N * H2_D * 2;
    const size_t SZ_H1  = (size_t)B_SZ * H1_D * 2;
    const size_t SZ_FIX = SZ_XB + SZ_W1T + SZ_W2T + SZ_W3T;

    char* ws = (char*)d_ws;
    bf16* Xb  = (bf16*)ws;
    bf16* W1T = (bf16*)(ws + SZ_XB);
    bf16* W2T = (bf16*)(ws + SZ_XB + SZ_W1T);
    bf16* W3T = (bf16*)(ws + SZ_XB + SZ_W1T + SZ_W2T);
    char* hbase = ws + SZ_FIX;

    // largest G (agents per pass) that fits: h1 only (h2/L3 fused)
    int G = 8;
    while (G > 1 && ws_size < SZ_FIX + (size_t)G * SZ_H1) G >>= 1;

    (void)hipFuncSetAttribute((const void*)k_gemm256<0>,
                              hipFuncAttributeMaxDynamicSharedMemorySize, 131072);
    (void)hipFuncSetAttribute((const void*)k_gemm256<1>,
                              hipFuncAttributeMaxDynamicSharedMemorySize, 131072);

    // out = b3 broadcast (fused L3 accumulates on top)
    k_init_out<<<(B_SZ * 128 + 255) / 256, 256, 0, stream>>>(b3, out);

    // preprocessing
    {
        int n = B_SZ * (IN_DD / 8);
        k_convert_x<<<(n + 255) / 256, 256, 0, stream>>>(obs, act, Xb);
    }
    k_transpose_w<<<dim3(IN_DD / 32, H1_D / 32, NAGENT), dim3(32, 8), 0, stream>>>(
        W1, W1T, IN_DD, H1_D, OBS_DD);
    k_transpose_w<<<dim3(H1_D / 32, H2_D / 32, NAGENT), dim3(32, 8), 0, stream>>>(
        W2, W2T, H1_D, H2_D, 1 << 30);
    {
        int n = NAGENT * NA_N * H2_D;
        k_transpose_w3<<<(n + 255) / 256, 256, 0, stream>>>(W3, W3T);
    }

    const size_t agElems = (size_t)B_SZ * H1_D;
    bf16* h1 = (bf16*)hbase;

    for (int g0 = 0; g0 < NAGENT; g0 += G) {
        k_gemm256<0><<<dim3(GRID_M, GRID_N, G), 256, 131072, stream>>>(
            Xb, 0, IN_DD, W1T, b1, h1, agElems, IN_DD, g0, G, nullptr, nullptr);
        k_gemm256<1><<<dim3(GRID_M, GRID_N, G), 256, 131072, stream>>>(
            h1, agElems, H1_D, W2T, b2, nullptr, 0, H1_D, g0, G, W3T, out);
    }
    (void)in_sizes; (void)n_in; (void)out_size;
}